// Round 8
// baseline (202.960 us; speedup 1.0000x reference)
//
#include <hip/hip_runtime.h>

#define DM 128
#define DFF 512
#define CLAMP_V 5.0f
#define LN_EPS 1e-5f

typedef __attribute__((ext_vector_type(8))) short bf16x8;
typedef __attribute__((ext_vector_type(4))) float f32x4;

__device__ __forceinline__ float b2f(ushort u) {
  union { uint u; float f; } x; x.u = ((uint)u) << 16; return x.f;
}
__device__ __forceinline__ ushort f2b(float f) {
  union { float f; uint u; } x; x.f = f;
  uint r = x.u + 0x7FFFu + ((x.u >> 16) & 1u);
  return (ushort)(r >> 16);
}
__device__ __forceinline__ void unpackw(uint w, float& lo, float& hi) {
  union { uint u; float f; } A, B;
  A.u = w << 16; B.u = w & 0xFFFF0000u;
  lo = A.f; hi = B.f;
}
__device__ __forceinline__ void unpack8w(uint4 w, float* o) {
  unpackw(w.x, o[0], o[1]); unpackw(w.y, o[2], o[3]);
  unpackw(w.z, o[4], o[5]); unpackw(w.w, o[6], o[7]);
}

// ---------------- casts ----------------
__global__ void k_cast(const float* __restrict__ s, ushort* __restrict__ d, int n) {
  int i4 = (blockIdx.x * blockDim.x + threadIdx.x) * 4;
  if (i4 + 3 < n) {
    float4 v = *reinterpret_cast<const float4*>(s + i4);
    ushort4 o; o.x = f2b(v.x); o.y = f2b(v.y); o.z = f2b(v.z); o.w = f2b(v.w);
    *reinterpret_cast<ushort4*>(d + i4) = o;
  } else {
    for (; i4 < n; ++i4) d[i4] = f2b(s[i4]);
  }
}

__global__ void k_castw(const float* __restrict__ wq, const float* __restrict__ wk,
                        const float* __restrict__ wv, const float* __restrict__ wo,
                        const float* __restrict__ w1, const float* __restrict__ w2,
                        ushort* __restrict__ d) {
  int i4 = (blockIdx.x * blockDim.x + threadIdx.x) * 4;
  if (i4 >= 196608) return;
  const float* s; int o;
  if      (i4 < 16384)  { s = wq; o = i4; }
  else if (i4 < 32768)  { s = wk; o = i4 - 16384; }
  else if (i4 < 49152)  { s = wv; o = i4 - 32768; }
  else if (i4 < 65536)  { s = wo; o = i4 - 49152; }
  else if (i4 < 131072) { s = w1; o = i4 - 65536; }
  else                  { s = w2; o = i4 - 131072; }
  float4 v = *reinterpret_cast<const float4*>(s + o);
  ushort4 u; u.x = f2b(v.x); u.y = f2b(v.y); u.z = f2b(v.z); u.w = f2b(v.w);
  *reinterpret_cast<ushort4*>(d + i4) = u;
}

// ---------------- CSR build ----------------
__global__ void k_count(const int* __restrict__ dst, int* __restrict__ deg, int E) {
  int e = blockIdx.x * blockDim.x + threadIdx.x;
  if (e < E) atomicAdd(&deg[dst[e]], 1);
}

#define SC_EPB 1024

__global__ __launch_bounds__(256) void k_scan1(const int* __restrict__ deg,
                                               int* __restrict__ off,
                                               int* __restrict__ bsum, int n) {
  __shared__ int sh[256];
  const int t = threadIdx.x;
  int base = blockIdx.x * SC_EPB + t * 4;
  int4 v = {0, 0, 0, 0};
  if (base + 3 < n) {
    v = *reinterpret_cast<const int4*>(deg + base);
  } else {
    if (base     < n) v.x = deg[base];
    if (base + 1 < n) v.y = deg[base + 1];
    if (base + 2 < n) v.z = deg[base + 2];
    if (base + 3 < n) v.w = deg[base + 3];
  }
  int s = v.x + v.y + v.z + v.w;
  sh[t] = s;
  __syncthreads();
  #pragma unroll
  for (int d = 1; d < 256; d <<= 1) {
    int x = 0;
    if (t >= d) x = sh[t - d];
    __syncthreads();
    sh[t] += x;
    __syncthreads();
  }
  int ex = sh[t] - s;
  if (base + 3 < n) {
    int4 o; o.x = ex; o.y = ex + v.x; o.z = ex + v.x + v.y; o.w = ex + v.x + v.y + v.z;
    *reinterpret_cast<int4*>(off + base) = o;
  } else {
    if (base     < n) off[base]     = ex;
    if (base + 1 < n) off[base + 1] = ex + v.x;
    if (base + 2 < n) off[base + 2] = ex + v.x + v.y;
    if (base + 3 < n) off[base + 3] = ex + v.x + v.y + v.z;
  }
  if (t == 255) bsum[blockIdx.x] = sh[255];
}

__global__ __launch_bounds__(256) void k_scan2(int* __restrict__ bsum, int nb) {
  __shared__ int sh[256];
  const int t = threadIdx.x;
  int v = (t < nb) ? bsum[t] : 0;
  sh[t] = v;
  __syncthreads();
  #pragma unroll
  for (int d = 1; d < 256; d <<= 1) {
    int x = 0;
    if (t >= d) x = sh[t - d];
    __syncthreads();
    sh[t] += x;
    __syncthreads();
  }
  if (t < nb) bsum[t] = sh[t] - v;
}

__global__ __launch_bounds__(256) void k_scan3(int* __restrict__ off,
                                               const int* __restrict__ bsum,
                                               int n, int E) {
  int add = bsum[blockIdx.x];
  int base = blockIdx.x * SC_EPB + threadIdx.x * 4;
  if (base + 3 < n) {
    int4 v = *reinterpret_cast<int4*>(off + base);
    v.x += add; v.y += add; v.z += add; v.w += add;
    *reinterpret_cast<int4*>(off + base) = v;
  } else {
    if (base     < n) off[base]     += add;
    if (base + 1 < n) off[base + 1] += add;
    if (base + 2 < n) off[base + 2] += add;
  }
  if (blockIdx.x == 0 && threadIdx.x == 0) off[n] = E;
}

__global__ void k_scatter(const int* __restrict__ src, const int* __restrict__ dst,
                          const int* __restrict__ off, int* __restrict__ cur,
                          int* __restrict__ csr, int E) {
  int e = blockIdx.x * blockDim.x + threadIdx.x;
  if (e < E) {
    int d = dst[e];
    int p = off[d] + atomicAdd(&cur[d], 1);
    csr[p] = src[e];
  }
}

// =====================================================================
// k_mmT: one-tile-per-block GEMM for K=128. Stage A tile (128x128) + B
// panel (128x128) to LDS, 8 waves (2 row x 4 col of 64x32), 32 MFMA each.
// FLAGS: 1=bias 2=relu 4=residual(f32,128w) 8=LN (requires gridDim.x==1)
// =====================================================================
template<int FLAGS, bool QKVSPLIT, bool OUTF, bool OUTB>
__global__ __launch_bounds__(512, 4) void k_mmT(
    const ushort* __restrict__ A, const ushort* __restrict__ W,
    const float* __restrict__ bias, const float* __restrict__ res,
    const float* __restrict__ lng, const float* __restrict__ lnbv,
    float* __restrict__ Cf, ushort* __restrict__ Cb, ushort* __restrict__ Cb2,
    int M, int ldc)
{
  __shared__ ushort As[128 * 128];
  __shared__ ushort Bs[128 * 128];
  __shared__ float lnred[(FLAGS & 8) ? 1024 : 4];

  const int tid = threadIdx.x;
  const int wv = tid >> 6, ln = tid & 63;
  const int bnb = blockIdx.x;
  const int mbase = blockIdx.y * 128;
  const int wrow = (wv >> 2) * 64, wcol = (wv & 3) * 32;
  const int o_base = tid * 16;

  // stage A tile + B panel (256B rows, 16-chunk XOR swizzle both-sides)
  #pragma unroll
  for (int is = 0; is < 4; ++is) {
    int o = is * 8192 + o_base;
    int row = o >> 8;
    int c = ((o >> 4) & 15) ^ (row & 15);
    int gr = min(mbase + row, M - 1);
    const ushort* sA = A + (size_t)gr * 128 + c * 8;
    __builtin_amdgcn_global_load_lds(
        (const __attribute__((address_space(1))) void*)sA,
        (__attribute__((address_space(3))) void*)((char*)As + is * 8192 + wv * 1024),
        16, 0, 0);
    const ushort* sB = W + (size_t)(bnb * 128 + row) * 128 + c * 8;
    __builtin_amdgcn_global_load_lds(
        (const __attribute__((address_space(1))) void*)sB,
        (__attribute__((address_space(3))) void*)((char*)Bs + is * 8192 + wv * 1024),
        16, 0, 0);
  }
  __syncthreads();

  f32x4 acc[4][2] = {};
  const char* AsB = (const char*)As;
  const char* BsB = (const char*)Bs;
  #pragma unroll
  for (int kk = 0; kk < 4; ++kk) {
    bf16x8 af[4], bfr[2];
    #pragma unroll
    for (int m = 0; m < 4; ++m) {
      int r = wrow + m * 16 + (ln & 15);
      int c = kk * 4 + (ln >> 4);
      af[m] = *reinterpret_cast<const bf16x8*>(AsB + r * 256 + ((c ^ (r & 15)) << 4));
    }
    #pragma unroll
    for (int n = 0; n < 2; ++n) {
      int r = wcol + n * 16 + (ln & 15);
      int c = kk * 4 + (ln >> 4);
      bfr[n] = *reinterpret_cast<const bf16x8*>(BsB + r * 256 + ((c ^ (r & 15)) << 4));
    }
    #pragma unroll
    for (int m = 0; m < 4; ++m)
      #pragma unroll
      for (int n = 0; n < 2; ++n)
        acc[m][n] = __builtin_amdgcn_mfma_f32_16x16x32_bf16(af[m], bfr[n], acc[m][n], 0, 0, 0);
  }

  if constexpr ((FLAGS & 8) != 0) {
    // ---- fused register-space LN epilogue (gridDim.x == 1, 128 cols) ----
    #pragma unroll
    for (int m = 0; m < 4; ++m)
      #pragma unroll
      for (int n = 0; n < 2; ++n) {
        int gc = wcol + n * 16 + (ln & 15);
        #pragma unroll
        for (int r = 0; r < 4; ++r) {
          int gr = mbase + wrow + m * 16 + (ln >> 4) * 4 + r;
          float v = acc[m][n][r];
          if (FLAGS & 1) v += bias[gc];
          if (FLAGS & 2) v = fmaxf(v, 0.f);
          if (FLAGS & 4) v += res[(size_t)min(gr, M - 1) * 128 + gc];
          acc[m][n][r] = v;
        }
      }
    #pragma unroll
    for (int m = 0; m < 4; ++m)
      #pragma unroll
      for (int r = 0; r < 4; ++r) {
        float sm = acc[m][0][r] + acc[m][1][r];
        float sq = acc[m][0][r] * acc[m][0][r] + acc[m][1][r] * acc[m][1][r];
        #pragma unroll
        for (int msk = 1; msk <= 8; msk <<= 1) {
          sm += __shfl_xor(sm, msk);
          sq += __shfl_xor(sq, msk);
        }
        if ((ln & 15) == 0) {
          int row = wrow + m * 16 + (ln >> 4) * 4 + r;
          lnred[row * 8 + (wv & 3) * 2]     = sm;
          lnred[row * 8 + (wv & 3) * 2 + 1] = sq;
        }
      }
    __syncthreads();
    #pragma unroll
    for (int m = 0; m < 4; ++m)
      #pragma unroll
      for (int r = 0; r < 4; ++r) {
        int row = wrow + m * 16 + (ln >> 4) * 4 + r;
        int gr = mbase + row;
        float sm = lnred[row * 8] + lnred[row * 8 + 2] + lnred[row * 8 + 4] + lnred[row * 8 + 6];
        float sq = lnred[row * 8 + 1] + lnred[row * 8 + 3] + lnred[row * 8 + 5] + lnred[row * 8 + 7];
        float mu = sm * (1.f / 128.f);
        float var = fmaxf(sq * (1.f / 128.f) - mu * mu, 0.f);
        float rstd = rsqrtf(var + LN_EPS);
        if (gr < M) {
          #pragma unroll
          for (int n = 0; n < 2; ++n) {
            int gc = wcol + n * 16 + (ln & 15);
            float y = (acc[m][n][r] - mu) * rstd * lng[gc] + lnbv[gc];
            if (OUTF) Cf[(size_t)gr * 128 + gc] = y;
            if (OUTB) Cb[(size_t)gr * 128 + gc] = f2b(y);
          }
        }
      }
  } else {
    #pragma unroll
    for (int m = 0; m < 4; ++m) {
      int gr0 = mbase + wrow + m * 16 + (ln >> 4) * 4;
      #pragma unroll
      for (int n = 0; n < 2; ++n) {
        int gcl = wcol + n * 16 + (ln & 15);
        float bsv = (FLAGS & 1) ? bias[bnb * 128 + gcl] : 0.f;
        #pragma unroll
        for (int r = 0; r < 4; ++r) {
          int gr = gr0 + r;
          if (gr >= M) continue;
          float v = acc[m][n][r] + bsv;
          if (FLAGS & 2) v = fmaxf(v, 0.f);
          if (QKVSPLIT) {
            if (bnb == 0) Cb[(size_t)gr * 128 + gcl] = f2b(v);
            else          Cb2[(size_t)gr * 256 + (bnb - 1) * 128 + gcl] = f2b(v);
          } else {
            if (OUTF) Cf[(size_t)gr * ldc + bnb * 128 + gcl] = v;
            if (OUTB) Cb[(size_t)gr * ldc + bnb * 128 + gcl] = f2b(v);
          }
        }
      }
    }
  }
}

// =====================================================================
// k_mm2: K-looped GEMM (K=512 ffn2), double-buffered LDS, 2-phase order.
// =====================================================================
#define BM 128
#define BN 128
#define BK 64

template<int FLAGS, bool OUTF, bool OUTB>
__global__ __launch_bounds__(256, 2) void k_mm2(
    const ushort* __restrict__ A, const ushort* __restrict__ W,
    const float* __restrict__ bias, const float* __restrict__ res,
    const float* __restrict__ lng, const float* __restrict__ lnbv,
    float* __restrict__ Cf, ushort* __restrict__ Cb,
    int M, int NO, int K)
{
  __shared__ ushort As[2][BM * BK];
  __shared__ ushort Ws[2][BN * BK];
  __shared__ float lnred[(FLAGS & 8) ? 512 : 4];

  const int tid = threadIdx.x;
  const int wv = tid >> 6, ln = tid & 63;
  const int bm = blockIdx.y * BM, bn = blockIdx.x * BN;
  const int wrow = (wv >> 1) * 64, wcol = (wv & 1) * 64;
  const int o_base = wv * 1024 + ln * 16;

  auto STG = [&](int kidx, int b) {
    #pragma unroll
    for (int is = 0; is < 4; ++is) {
      int o = is * 4096 + o_base;
      int row = o >> 7;
      int c = ((o >> 4) & 7) ^ (row & 7);
      int gm = min(bm + row, M - 1);
      const ushort* sA = A + (size_t)gm * K + kidx * BK + c * 8;
      __builtin_amdgcn_global_load_lds(
          (const __attribute__((address_space(1))) void*)sA,
          (__attribute__((address_space(3))) void*)((char*)As[b] + is * 4096 + wv * 1024),
          16, 0, 0);
      int gn = bn + row;
      const ushort* sW = W + (size_t)gn * K + kidx * BK + c * 8;
      __builtin_amdgcn_global_load_lds(
          (const __attribute__((address_space(1))) void*)sW,
          (__attribute__((address_space(3))) void*)((char*)Ws[b] + is * 4096 + wv * 1024),
          16, 0, 0);
    }
  };

  f32x4 acc[4][4] = {};
  const int KT = K >> 6;
  STG(0, 0);
  __syncthreads();
  int buf = 0;
  for (int i = 0; i < KT; ++i) {
    if (i + 1 < KT) STG(i + 1, buf ^ 1);
    const char* AsB = (const char*)As[buf];
    const char* WsB = (const char*)Ws[buf];
    #pragma unroll
    for (int kk = 0; kk < 2; ++kk) {
      bf16x8 af[4], bfr[4];
      #pragma unroll
      for (int m = 0; m < 4; ++m) {
        int r = wrow + m * 16 + (ln & 15);
        int c = kk * 4 + (ln >> 4);
        af[m] = *reinterpret_cast<const bf16x8*>(AsB + r * 128 + ((c ^ (r & 7)) << 4));
      }
      #pragma unroll
      for (int n = 0; n < 4; ++n) {
        int r = wcol + n * 16 + (ln & 15);
        int c = kk * 4 + (ln >> 4);
        bfr[n] = *reinterpret_cast<const bf16x8*>(WsB + r * 128 + ((c ^ (r & 7)) << 4));
      }
      #pragma unroll
      for (int m = 0; m < 4; ++m)
        #pragma unroll
        for (int n = 0; n < 4; ++n)
          acc[m][n] = __builtin_amdgcn_mfma_f32_16x16x32_bf16(af[m], bfr[n], acc[m][n], 0, 0, 0);
    }
    __syncthreads();
    buf ^= 1;
  }

  if constexpr ((FLAGS & 8) != 0) {
    #pragma unroll
    for (int m = 0; m < 4; ++m)
      #pragma unroll
      for (int n = 0; n < 4; ++n) {
        int gc = wcol + n * 16 + (ln & 15);
        float bsv = (FLAGS & 1) ? bias[gc] : 0.f;
        #pragma unroll
        for (int r = 0; r < 4; ++r) {
          int gr = bm + wrow + m * 16 + (ln >> 4) * 4 + r;
          float v = acc[m][n][r] + bsv;
          if (FLAGS & 2) v = fmaxf(v, 0.f);
          if (FLAGS & 4) v += res[(size_t)min(gr, M - 1) * 128 + gc];
          acc[m][n][r] = v;
        }
      }
    #pragma unroll
    for (int m = 0; m < 4; ++m)
      #pragma unroll
      for (int r = 0; r < 4; ++r) {
        float sm = acc[m][0][r] + acc[m][1][r] + acc[m][2][r] + acc[m][3][r];
        float sq = acc[m][0][r] * acc[m][0][r] + acc[m][1][r] * acc[m][1][r]
                 + acc[m][2][r] * acc[m][2][r] + acc[m][3][r] * acc[m][3][r];
        #pragma unroll
        for (int msk = 1; msk <= 8; msk <<= 1) {
          sm += __shfl_xor(sm, msk);
          sq += __shfl_xor(sq, msk);
        }
        if ((ln & 15) == 0) {
          int row = wrow + m * 16 + (ln >> 4) * 4 + r;
          lnred[row * 4 + (wv & 1) * 2]     = sm;
          lnred[row * 4 + (wv & 1) * 2 + 1] = sq;
        }
      }
    __syncthreads();
    #pragma unroll
    for (int m = 0; m < 4; ++m)
      #pragma unroll
      for (int r = 0; r < 4; ++r) {
        int row = wrow + m * 16 + (ln >> 4) * 4 + r;
        int gr = bm + row;
        float sm = lnred[row * 4] + lnred[row * 4 + 2];
        float sq = lnred[row * 4 + 1] + lnred[row * 4 + 3];
        float mu = sm * (1.f / 128.f);
        float var = fmaxf(sq * (1.f / 128.f) - mu * mu, 0.f);
        float rstd = rsqrtf(var + LN_EPS);
        if (gr < M) {
          #pragma unroll
          for (int n = 0; n < 4; ++n) {
            int gc = wcol + n * 16 + (ln & 15);
            float y = (acc[m][n][r] - mu) * rstd * lng[gc] + lnbv[gc];
            if (OUTF) Cf[(size_t)gr * 128 + gc] = y;
            if (OUTB) Cb[(size_t)gr * 128 + gc] = f2b(y);
          }
        }
      }
  } else {
    #pragma unroll
    for (int m = 0; m < 4; ++m) {
      int gr0 = bm + wrow + m * 16 + (ln >> 4) * 4;
      #pragma unroll
      for (int n = 0; n < 4; ++n) {
        int gc = bn + wcol + n * 16 + (ln & 15);
        float bsv = (FLAGS & 1) ? bias[gc] : 0.f;
        #pragma unroll
        for (int r = 0; r < 4; ++r) {
          int gr = gr0 + r;
          if (gr >= M) continue;
          float v = acc[m][n][r] + bsv;
          if (FLAGS & 2) v = fmaxf(v, 0.f);
          if (FLAGS & 4) v += res[(size_t)gr * NO + gc];
          if (OUTF) Cf[(size_t)gr * NO + gc] = v;
          if (OUTB) Cb[(size_t)gr * NO + gc] = f2b(v);
        }
      }
    }
  }
}

// ---------------- edge-softmax attention: fixed-max + reg double-buffered KV ----
// 8 groups x 8 lanes, lane = full head. KV for iter i+1 loaded into the
// alternate register set before computing iter i (static ping-pong).
__global__ __launch_bounds__(256) void k_attn(
    const ushort* __restrict__ q, const ushort* __restrict__ kv,
    const int* __restrict__ off, const int* __restrict__ csr,
    ushort* __restrict__ sav, int n)
{
  int node = blockIdx.x * 4 + (threadIdx.x >> 6);
  int lane = threadIdx.x & 63;
  if (node >= n) return;
  const int g = lane >> 3, sl = lane & 7;

  const ushort* qr = q + (size_t)node * 128 + sl * 16;
  uint4 qw0 = *reinterpret_cast<const uint4*>(qr);
  uint4 qw1 = *reinterpret_cast<const uint4*>(qr + 8);
  float qv[16];
  unpack8w(qw0, qv); unpack8w(qw1, qv + 8);

  int b = off[node], e = off[node + 1];
  float s = 0.f;
  float a[16] = {};
  int nIt = (e - b + 7) >> 3;

  if (nIt > 0) {
    int idx = b + g;
    int snA = csr[min(idx, e - 1)];
    const ushort* krA = kv + (size_t)snA * 256 + sl * 16;
    uint4 kA0 = *reinterpret_cast<const uint4*>(krA);
    uint4 kA1 = *reinterpret_cast<const uint4*>(krA + 8);
    uint4 vA0 = *reinterpret_cast<const uint4*>(krA + 128);
    uint4 vA1 = *reinterpret_cast<const uint4*>(krA + 136);
    int snB = (nIt > 1) ? csr[min(idx + 8, e - 1)] : 0;
    uint4 kB0, kB1, vB0, vB1;
    int i = 0;

    #define ATT_COMPUTE(K0, K1, V0, V1)                                  \
      {                                                                  \
        float kk[16];                                                    \
        unpack8w(K0, kk); unpack8w(K1, kk + 8);                          \
        float p = 0.f;                                                   \
        _Pragma("unroll")                                                \
        for (int j = 0; j < 16; ++j) p = fmaf(qv[j], kk[j], p);          \
        float u = fminf(fmaxf(p * 0.25f, -CLAMP_V), CLAMP_V);            \
        float w = __expf(u - CLAMP_V);                                   \
        w = (idx < e) ? w : 0.f;                                         \
        s += w;                                                          \
        float vvv[16];                                                   \
        unpack8w(V0, vvv); unpack8w(V1, vvv + 8);                        \
        _Pragma("unroll")                                                \
        for (int j = 0; j < 16; ++j) a[j] = fmaf(w, vvv[j], a[j]);       \
      }

    while (true) {
      // compute A (iter i); prefetch B (iter i+1) and snC (iter i+2)
      if (i + 1 < nIt) {
        const ushort* kr = kv + (size_t)snB * 256 + sl * 16;
        kB0 = *reinterpret_cast<const uint4*>(kr);
        kB1 = *reinterpret_cast<const uint4*>(kr + 8);
        vB0 = *reinterpret_cast<const uint4*>(kr + 128);
        vB1 = *reinterpret_cast<const uint4*>(kr + 136);
      }
      int snC = (i + 2 < nIt) ? csr[min(idx + 16, e - 1)] : 0;
      ATT_COMPUTE(kA0, kA1, vA0, vA1)
      idx += 8; ++i;
      if (i >= nIt) break;

      // compute B (iter i); prefetch A (iter i+1) and snD (iter i+2)
      if (i + 1 < nIt) {
        const ushort* kr = kv + (size_t)snC * 256 + sl * 16;
        kA0 = *reinterpret_cast<const uint4*>(kr);
        kA1 = *reinterpret_cast<const uint4*>(kr + 8);
        vA0 = *reinterpret_cast<const uint4*>(kr + 128);
        vA1 = *reinterpret_cast<const uint4*>(kr + 136);
      }
      int snD = (i + 2 < nIt) ? csr[min(idx + 16, e - 1)] : 0;
      ATT_COMPUTE(kB0, kB1, vB0, vB1)
      idx += 8; ++i;
      if (i >= nIt) break;
      snB = snD;
    }
    #undef ATT_COMPUTE
  }

  #pragma unroll
  for (int msk = 8; msk <= 32; msk <<= 1) {
    s += __shfl_xor(s, msk);
    #pragma unroll
    for (int j = 0; j < 16; ++j) a[j] += __shfl_xor(a[j], msk);
  }

  float inv = (s > 0.f) ? 1.f / s : 0.f;
  if (g == 0) {
    uint w[8];
    #pragma unroll
    for (int j = 0; j < 8; ++j)
      w[j] = (uint)f2b(a[2 * j] * inv) | ((uint)f2b(a[2 * j + 1] * inv) << 16);
    ushort* outp = sav + (size_t)node * 128 + sl * 16;
    uint4 o0 = {w[0], w[1], w[2], w[3]};
    uint4 o1 = {w[4], w[5], w[6], w[7]};
    *reinterpret_cast<uint4*>(outp) = o0;
    *reinterpret_cast<uint4*>(outp + 8) = o1;
  }
}

extern "C" void kernel_launch(void* const* d_in, const int* in_sizes, int n_in,
                              void* d_out, int out_size, void* d_ws, size_t ws_size,
                              hipStream_t stream)
{
  const float* feat = (const float*)d_in[0];
  const int*   src  = (const int*)d_in[1];
  const int*   dst  = (const int*)d_in[2];
  const float* Wq   = (const float*)d_in[3];
  const float* Wk   = (const float*)d_in[4];
  const float* Wv   = (const float*)d_in[5];
  const float* Wo   = (const float*)d_in[6];
  const float* ln1g = (const float*)d_in[7];
  const float* ln1b = (const float*)d_in[8];
  const float* W1   = (const float*)d_in[9];
  const float* b1   = (const float*)d_in[10];
  const float* W2   = (const float*)d_in[11];
  const float* b2   = (const float*)d_in[12];
  const float* ln2g = (const float*)d_in[13];
  const float* ln2b = (const float*)d_in[14];
  float* out = (float*)d_out;

  const int N = in_sizes[0] / DM;
  const int E = in_sizes[1];
  const size_t NB = (size_t)N;

  char* wsb = (char*)d_ws;
  ushort* q_bf    = (ushort*)wsb;
  ushort* kv_bf   = (ushort*)(wsb + NB * 256);
  ushort* sav_bf  = (ushort*)(wsb + NB * 768);
  ushort* mid_bf  = (ushort*)wsb;
  float*  h1      = (float*)(wsb + NB * 1024);
  ushort* h1b     = (ushort*)(wsb + NB * 1536);
  ushort* feat_bf = (ushort*)(wsb + NB * 1792);
  ushort* wbf     = (ushort*)(wsb + NB * 2048);
  ushort* wqkv_bf = wbf;
  ushort* wo_bf   = wbf + 49152;
  ushort* w1_bf   = wbf + 65536;
  ushort* w2_bf   = wbf + 131072;
  int* ib  = (int*)(wbf + 196608);
  int* deg = ib;
  int* cur = ib + N;
  int* off = ib + 2 * N;
  int* csr = ib + 3 * N + 1;
  int* bsum = csr + E;

  hipMemsetAsync(deg, 0, 2 * (size_t)N * sizeof(int), stream);

  int nf = N * DM;
  k_cast<<<(nf / 4 + 255) / 256, 256, 0, stream>>>(feat, feat_bf, nf);
  k_castw<<<192, 256, 0, stream>>>(Wq, Wk, Wv, Wo, W1, W2, wbf);

  int eb = (E + 255) / 256;
  int nbk = (N + SC_EPB - 1) / SC_EPB;
  k_count<<<eb, 256, 0, stream>>>(dst, deg, E);
  k_scan1<<<nbk, 256, 0, stream>>>(deg, off, bsum, N);
  k_scan2<<<1, 256, 0, stream>>>(bsum, nbk);
  k_scan3<<<nbk, 256, 0, stream>>>(off, bsum, N, E);
  k_scatter<<<eb, 256, 0, stream>>>(src, dst, off, cur, csr, E);

  int nb4 = (N + 3) / 4;
  const int nT = (N + 127) / 128;   // 313

  // qkv: grid (3, nT), split output q_bf | kv_bf
  k_mmT<0, true, false, true><<<dim3(3, nT), 512, 0, stream>>>(
      feat_bf, wqkv_bf, nullptr, nullptr, nullptr, nullptr,
      nullptr, q_bf, kv_bf, N, 128);

  k_attn<<<nb4, 256, 0, stream>>>(q_bf, kv_bf, off, csr, sav_bf, N);

  // h1 = LN1(sav @ Wo^T + feat) -> h1 f32 + h1b bf16
  k_mmT<4 | 8, false, true, true><<<dim3(1, nT), 512, 0, stream>>>(
      sav_bf, wo_bf, nullptr, feat, ln1g, ln1b, h1, h1b, nullptr, N, 128);

  // mid = relu(h1 @ W1^T + b1)
  k_mmT<1 | 2, false, false, true><<<dim3(4, nT), 512, 0, stream>>>(
      h1b, w1_bf, b1, nullptr, nullptr, nullptr,
      nullptr, mid_bf, nullptr, N, DFF);

  // out = LN2(mid @ W2^T + b2 + h1), K=512 double-buffered
  k_mm2<1 | 4 | 8, true, false><<<dim3(1, nT), 256, 0, stream>>>(
      mid_bf, w2_bf, b2, h1, ln2g, ln2b, out, nullptr, N, DM, DFF);
}